// Round 4
// baseline (17.123 us; speedup 1.0000x reference)
//
#include <hip/hip_runtime.h>
#include <math.h>

// Problem constants (from reference setup)
#define BATCH   8
#define NPTS    1024
#define MCTX    1024
#define BN      (BATCH * NPTS)
#define HALF    512                  // context points per wave (2 waves per row)

// FEATURES_RANGE = [50, 50, 32, 32, pi]; feature 4 is cyclic
#define INV_R0  0.02f
#define INV_R1  0.02f
#define INV_R2  0.03125f
#define INV_R3  0.03125f
#define INV_PI  0.3183098861837907f
#define MAX_DIST 50.0f
#define LOG2E   1.4426950408889634f

__global__ __launch_bounds__(512) void sim_kernel(
    const float* __restrict__ points,          // [B,N,5]
    const float* __restrict__ ctx,             // [B,M,5]
    const float* __restrict__ dist,            // [B,N,M]
    const unsigned char* __restrict__ imask,   // [B,N,M] bool as u8
    const int* __restrict__ gmd_p,             // scalar
    const float* __restrict__ W1p,             // [5,4] row-major
    const float* __restrict__ b1p,             // [4]
    const float* __restrict__ W2p,             // [4,1]
    const float* __restrict__ b2p,             // [1]
    const float* __restrict__ Wap,             // [5,1]
    const float* __restrict__ bap,             // [1]
    float* __restrict__ out)                   // [B,N]
{
    // 8 waves per block; wave pair (2r, 2r+1) handles row r (4 rows/block)
    __shared__ float sctx[MCTX * 5];            // 20 KB: ctx[b] staged (AoS)
    __shared__ unsigned short q[8][HALF];       // 8 KB: per-wave valid-offset queues
    __shared__ float smerge[8][2];              // cross-wave partial merge

    const int wid  = threadIdx.x >> 6;          // 0..7
    const int lane = threadIdx.x & 63;
    const int rloc = wid >> 1;                  // 0..3: row within block
    const int half = wid & 1;                   // which half of M this wave owns
    const int row  = blockIdx.x * 4 + rloc;     // (b*N + n)
    const int b    = row >> 10;

    // --- cooperative LDS stage of ctx[b]: 5120 floats = 1280 float4 ---
    {
        const float4* __restrict__ src = (const float4*)(ctx + (size_t)b * MCTX * 5);
        float4* dst = (float4*)sctx;
        for (int i = threadIdx.x; i < (MCTX * 5) / 4; i += 512)
            dst[i] = src[i];
    }
    __syncthreads();

    // --- tiny weights (uniform addresses -> scalar loads / SGPRs) ---
    float w1[20];
#pragma unroll
    for (int i = 0; i < 20; ++i) w1[i] = W1p[i];
    float b1v[4];
#pragma unroll
    for (int j = 0; j < 4; ++j) b1v[j] = b1p[j];
    // fold -log2(e) into W2/b2:  sigmoid(z) = 1/(1 + 2^(-z*log2e))
    float w2n[4];
#pragma unroll
    for (int j = 0; j < 4; ++j) w2n[j] = W2p[j] * (-LOG2E);
    const float b2n = b2p[0] * (-LOG2E);
    // fold +log2(e) into Wa/ba:  exp(score) = 2^(score*log2e)
    float wan[5];
#pragma unroll
    for (int f = 0; f < 5; ++f) wan[f] = Wap[f] * LOG2E;
    const float ban = bap[0] * LOG2E;

    // --- this row's point features (wave-uniform values) ---
    const float p0 = points[row * 5 + 0];
    const float p1 = points[row * 5 + 1];
    const float p2 = points[row * 5 + 2];
    const float p3 = points[row * 5 + 3];
    const float p4 = points[row * 5 + 4];

    const bool tighten = (MAX_DIST < (float)gmd_p[0]);
    const int  mbase = half * HALF;
    const float4*       __restrict__ d4 = (const float4*)(dist  + (size_t)row * MCTX + mbase);
    const unsigned int* __restrict__ m4 = (const unsigned int*)(imask + (size_t)row * MCTX + mbase);

    // --- load this wave's half: 2 float4 dist chunks + 2 dword mask chunks ---
    float4 dv0 = d4[lane];
    float4 dv1 = d4[lane + 64];
    unsigned int mv0 = m4[lane];
    unsigned int mv1 = m4[lane + 64];

    // --- precompute all 8 validity bits first (ILP: ballots independent) ---
    unsigned okbits = 0;
    {
        const float dd0[4] = { dv0.x, dv0.y, dv0.z, dv0.w };
        const float dd1[4] = { dv1.x, dv1.y, dv1.z, dv1.w };
#pragma unroll
        for (int t = 0; t < 4; ++t) {
            bool ok0 = ((mv0 >> (8 * t)) & 0xFFu) != 0u;
            bool ok1 = ((mv1 >> (8 * t)) & 0xFFu) != 0u;
            if (tighten) {
                ok0 = ok0 && (dd0[t] <= MAX_DIST);
                ok1 = ok1 && (dd1[t] <= MAX_DIST);
            }
            okbits |= ok0 ? (1u << t)       : 0u;
            okbits |= ok1 ? (1u << (4 + t)) : 0u;
        }
    }

    // --- compaction: enqueue sctx byte-offsets (20*m) of valid pairs ---
    int tot = 0;
#pragma unroll
    for (int k = 0; k < 8; ++k) {
        const int j = k >> 2, t = k & 3;       // j: chunk, t: byte within dword
        const bool ok = (okbits >> (j * 4 + t)) & 1u;
        unsigned long long bm = __ballot(ok);
        unsigned rank = __builtin_amdgcn_mbcnt_hi(
                            (unsigned)(bm >> 32),
                            __builtin_amdgcn_mbcnt_lo((unsigned)bm, 0u));
        if (ok) {
            const int m = mbase + (lane + 64 * j) * 4 + t;
            q[wid][tot + rank] = (unsigned short)(20 * m);
        }
        tot += (int)__popcll(bm);
    }

    // --- fused MLP + softmax over the compacted set (~2 groups per wave) ---
    float lsum = 0.0f, asum = 0.0f;
    const char* __restrict__ cbase = (const char*)sctx;
#pragma unroll 2
    for (int i = lane; i < tot; i += 64) {
        const int off = (int)q[wid][i];
        const float* __restrict__ c = (const float*)(cbase + off);
        const float c0 = c[0], c1 = c[1], c2 = c[2], c3 = c[3], c4 = c[4];

        float fn0 = fabsf(p0 - c0) * INV_R0;
        float fn1 = fabsf(p1 - c1) * INV_R1;
        float fn2 = fabsf(p2 - c2) * INV_R2;
        float fn3 = fabsf(p3 - c3) * INV_R3;
        float g   = __builtin_amdgcn_fractf(fabsf(p4 - c4) * INV_PI); // rem(x,1), x>=0
        float fn4 = fminf(g, 1.0f - g);        // cyclic wrap distance

        // h = relu(fn @ W1 + b1), W1 row-major [5,4]
        float h0 = fmaxf(0.0f, b1v[0] + fn0*w1[0]  + fn1*w1[4]  + fn2*w1[8]  + fn3*w1[12] + fn4*w1[16]);
        float h1 = fmaxf(0.0f, b1v[1] + fn0*w1[1]  + fn1*w1[5]  + fn2*w1[9]  + fn3*w1[13] + fn4*w1[17]);
        float h2 = fmaxf(0.0f, b1v[2] + fn0*w1[2]  + fn1*w1[6]  + fn2*w1[10] + fn3*w1[14] + fn4*w1[18]);
        float h3 = fmaxf(0.0f, b1v[3] + fn0*w1[3]  + fn1*w1[7]  + fn2*w1[11] + fn3*w1[15] + fn4*w1[19]);

        // zn = -z*log2e ;  energy = sigmoid(z) = rcp(1 + 2^zn)
        float zn = b2n + h0*w2n[0] + h1*w2n[1] + h2*w2n[2] + h3*w2n[3];
        float energy = __builtin_amdgcn_rcpf(1.0f + __builtin_amdgcn_exp2f(zn));

        // e = exp(score) = 2^(score*log2e)   (scores bounded: no max needed)
        float sc = ban + fn0*wan[0] + fn1*wan[1] + fn2*wan[2] + fn3*wan[3] + fn4*wan[4];
        float e  = __builtin_amdgcn_exp2f(sc);

        lsum += e;
        asum = fmaf(e, energy, asum);
    }

    // --- 64-lane butterfly sum of (lsum, asum) ---
#pragma unroll
    for (int off = 1; off < 64; off <<= 1) {
        lsum += __shfl_xor(lsum, off, 64);
        asum += __shfl_xor(asum, off, 64);
    }

    // --- cross-wave merge: wave pair (2r, 2r+1) -> row r ---
    if (lane == 0) {
        smerge[wid][0] = lsum;
        smerge[wid][1] = asum;
    }
    __syncthreads();
    if (half == 0 && lane == 0) {
        const float L = smerge[wid][0] + smerge[wid + 1][0];
        const float A = smerge[wid][1] + smerge[wid + 1][1];
        out[row] = (L > 0.0f) ? (A / L) : 0.0f;    // all-masked -> 0
    }
}

extern "C" void kernel_launch(void* const* d_in, const int* in_sizes, int n_in,
                              void* d_out, int out_size, void* d_ws, size_t ws_size,
                              hipStream_t stream) {
    const float*         points = (const float*)d_in[0];
    // d_in[1] points_mask: unused by reference
    const float*         ctx    = (const float*)d_in[2];
    // d_in[3] context_points_mask: unused by reference
    const float*         dist   = (const float*)d_in[4];
    const unsigned char* imask  = (const unsigned char*)d_in[5];
    const int*           gmd    = (const int*)d_in[6];
    const float*         W1     = (const float*)d_in[7];
    const float*         b1     = (const float*)d_in[8];
    const float*         W2     = (const float*)d_in[9];
    const float*         b2     = (const float*)d_in[10];
    const float*         Wa     = (const float*)d_in[11];
    const float*         ba     = (const float*)d_in[12];
    float*               out    = (float*)d_out;

    dim3 block(512);            // 8 waves: 4 rows x 2 waves/row
    dim3 grid(BN / 4);          // 2048 blocks -> 2 generations/CU (phase overlap)
    sim_kernel<<<grid, block, 0, stream>>>(points, ctx, dist, imask, gmd,
                                           W1, b1, W2, b2, Wa, ba, out);
}

// Round 5
// 15.466 us; speedup vs baseline: 1.1072x; 1.1072x over previous
//
#include <hip/hip_runtime.h>
#include <math.h>

// Problem constants (from reference setup)
#define BATCH   8
#define NPTS    1024
#define MCTX    1024
#define BN      (BATCH * NPTS)

// FEATURES_RANGE = [50, 50, 32, 32, pi]; feature 4 is cyclic
#define INV_R0  0.02f
#define INV_R1  0.02f
#define INV_R2  0.03125f
#define INV_R3  0.03125f
#define INV_PI  0.3183098861837907f
#define MAX_DIST 50.0f
#define LOG2E   1.4426950408889634f

__global__ __launch_bounds__(512) void sim_kernel(
    const float* __restrict__ points,          // [B,N,5]
    const float* __restrict__ ctx,             // [B,M,5]
    const float* __restrict__ dist,            // [B,N,M]
    const unsigned char* __restrict__ imask,   // [B,N,M] bool as u8
    const int* __restrict__ gmd_p,             // scalar
    const float* __restrict__ W1p,             // [5,4] row-major
    const float* __restrict__ b1p,             // [4]
    const float* __restrict__ W2p,             // [4,1]
    const float* __restrict__ b2p,             // [1]
    const float* __restrict__ Wap,             // [5,1]
    const float* __restrict__ bap,             // [1]
    float* __restrict__ out)                   // [B,N]
{
    // 8 waves per block, one full row per wave (R3 shape — R4's split regressed)
    __shared__ float4         sA[MCTX];        // 16 KB: c0..c3 per m (aligned b128 gather)
    __shared__ float          s4[MCTX];        //  4 KB: c4 * (1/pi)
    __shared__ unsigned short q[8][MCTX];      // 16 KB: per-wave valid m queues

    const int wid  = threadIdx.x >> 6;         // 0..7
    const int lane = threadIdx.x & 63;
    const int row  = blockIdx.x * 8 + wid;     // (b*N + n)
    const int b    = row >> 10;

    // ---------- phase 1: issue ALL global loads up front ----------
    // ctx stage: thread handles records m0 and m0+512 (20B apart, 4B-aligned)
    const float* __restrict__ cb = ctx + (size_t)b * MCTX * 5;
    const int m0 = threadIdx.x, m1 = threadIdx.x + 512;
    const float r00 = cb[m0*5+0], r01 = cb[m0*5+1], r02 = cb[m0*5+2],
                r03 = cb[m0*5+3], r04 = cb[m0*5+4];
    const float r10 = cb[m1*5+0], r11 = cb[m1*5+1], r12 = cb[m1*5+2],
                r13 = cb[m1*5+3], r14 = cb[m1*5+4];

    // dist + mask for this wave's row (in flight across the barrier)
    const float4*       __restrict__ d4  = (const float4*)(dist + (size_t)row * MCTX);
    const unsigned int* __restrict__ m4p = (const unsigned int*)(imask + (size_t)row * MCTX);
    float4 dv0 = d4[lane],       dv1 = d4[lane + 64],
           dv2 = d4[lane + 128], dv3 = d4[lane + 192];
    unsigned int mv0 = m4p[lane],       mv1 = m4p[lane + 64],
                 mv2 = m4p[lane + 128], mv3 = m4p[lane + 192];

    // ---------- phase 2: LDS stage + barrier ----------
    sA[m0] = make_float4(r00, r01, r02, r03);
    s4[m0] = r04 * INV_PI;
    sA[m1] = make_float4(r10, r11, r12, r13);
    s4[m1] = r14 * INV_PI;
    __syncthreads();

    // ---------- weights (uniform -> scalar loads), range-folded ----------
    const float ir[4] = { INV_R0, INV_R1, INV_R2, INV_R3 };
    float w1s[20];                              // W1 with 1/range folded into rows 0..3
#pragma unroll
    for (int f = 0; f < 5; ++f) {
        const float s = (f < 4) ? ir[f] : 1.0f;
#pragma unroll
        for (int j = 0; j < 4; ++j) w1s[f*4+j] = W1p[f*4+j] * s;
    }
    float b1v[4];
#pragma unroll
    for (int j = 0; j < 4; ++j) b1v[j] = b1p[j];
    float w2n[4];                               // -log2e folded: sigmoid via exp2
#pragma unroll
    for (int j = 0; j < 4; ++j) w2n[j] = W2p[j] * (-LOG2E);
    const float b2n = b2p[0] * (-LOG2E);
    float wan[5];                               // +log2e (and 1/range) folded
#pragma unroll
    for (int f = 0; f < 5; ++f) wan[f] = Wap[f] * LOG2E * ((f < 4) ? ir[f] : 1.0f);
    const float ban = bap[0] * LOG2E;

    // this row's point features
    const float p0 = points[row*5+0], p1 = points[row*5+1], p2 = points[row*5+2],
                p3 = points[row*5+3], p4s = points[row*5+4] * INV_PI;

    const bool tighten = (MAX_DIST < (float)gmd_p[0]);

    // ---------- validity bits (16 pairs per lane) ----------
    unsigned okbits = 0;
    {
        const float4 dvv[4] = { dv0, dv1, dv2, dv3 };
        const unsigned int mvv[4] = { mv0, mv1, mv2, mv3 };
#pragma unroll
        for (int j = 0; j < 4; ++j) {
            const float dd[4] = { dvv[j].x, dvv[j].y, dvv[j].z, dvv[j].w };
#pragma unroll
            for (int t = 0; t < 4; ++t) {
                bool ok = ((mvv[j] >> (8*t)) & 0xFFu) != 0u;
                if (tighten) ok = ok && (dd[t] <= MAX_DIST);
                okbits |= ok ? (1u << (4*j + t)) : 0u;
            }
        }
    }

    // ---------- compaction: valid m-indices into q[wid] ----------
    int tot = 0;
#pragma unroll
    for (int k = 0; k < 16; ++k) {
        const bool ok = (okbits >> k) & 1u;
        unsigned long long bm = __ballot(ok);
        unsigned rank = __builtin_amdgcn_mbcnt_hi(
                            (unsigned)(bm >> 32),
                            __builtin_amdgcn_mbcnt_lo((unsigned)bm, 0u));
        if (ok) {
            const int m = (lane + 64 * (k >> 2)) * 4 + (k & 3);
            q[wid][tot + rank] = (unsigned short)m;
        }
        tot += (int)__popcll(bm);
    }

    // ---------- fused MLP + softmax over compacted set ----------
    float lsum = 0.0f, asum = 0.0f;
#pragma unroll 2
    for (int i = lane; i < tot; i += 64) {
        const int m = (int)q[wid][i];
        const float4 cA  = sA[m];               // one ds_read_b128
        const float  c4v = s4[m];               // one ds_read_b32

        // raw abs-diffs; 1/range lives in the weights (abs folds into VOP3 mods)
        const float a0 = fabsf(p0 - cA.x);
        const float a1 = fabsf(p1 - cA.y);
        const float a2 = fabsf(p2 - cA.z);
        const float a3 = fabsf(p3 - cA.w);
        float g   = __builtin_amdgcn_fractf(fabsf(p4s - c4v));  // both pre-scaled by 1/pi
        float fn4 = fminf(g, 1.0f - g);

        float h0 = fmaxf(0.0f, b1v[0] + a0*w1s[0] + a1*w1s[4] + a2*w1s[8]  + a3*w1s[12] + fn4*w1s[16]);
        float h1 = fmaxf(0.0f, b1v[1] + a0*w1s[1] + a1*w1s[5] + a2*w1s[9]  + a3*w1s[13] + fn4*w1s[17]);
        float h2 = fmaxf(0.0f, b1v[2] + a0*w1s[2] + a1*w1s[6] + a2*w1s[10] + a3*w1s[14] + fn4*w1s[18]);
        float h3 = fmaxf(0.0f, b1v[3] + a0*w1s[3] + a1*w1s[7] + a2*w1s[11] + a3*w1s[15] + fn4*w1s[19]);

        float zn = b2n + h0*w2n[0] + h1*w2n[1] + h2*w2n[2] + h3*w2n[3];
        float energy = __builtin_amdgcn_rcpf(1.0f + __builtin_amdgcn_exp2f(zn));

        float sc = ban + a0*wan[0] + a1*wan[1] + a2*wan[2] + a3*wan[3] + fn4*wan[4];
        float e  = __builtin_amdgcn_exp2f(sc);

        lsum += e;
        asum = fmaf(e, energy, asum);
    }

    // ---------- 64-lane butterfly sum ----------
#pragma unroll
    for (int off = 1; off < 64; off <<= 1) {
        lsum += __shfl_xor(lsum, off, 64);
        asum += __shfl_xor(asum, off, 64);
    }

    if (lane == 0) {
        out[row] = (lsum > 0.0f) ? (asum / lsum) : 0.0f;   // all-masked -> 0
    }
}

extern "C" void kernel_launch(void* const* d_in, const int* in_sizes, int n_in,
                              void* d_out, int out_size, void* d_ws, size_t ws_size,
                              hipStream_t stream) {
    const float*         points = (const float*)d_in[0];
    // d_in[1] points_mask: unused by reference
    const float*         ctx    = (const float*)d_in[2];
    // d_in[3] context_points_mask: unused by reference
    const float*         dist   = (const float*)d_in[4];
    const unsigned char* imask  = (const unsigned char*)d_in[5];
    const int*           gmd    = (const int*)d_in[6];
    const float*         W1     = (const float*)d_in[7];
    const float*         b1     = (const float*)d_in[8];
    const float*         W2     = (const float*)d_in[9];
    const float*         b2     = (const float*)d_in[10];
    const float*         Wa     = (const float*)d_in[11];
    const float*         ba     = (const float*)d_in[12];
    float*               out    = (float*)d_out;

    dim3 block(512);            // 8 waves, one row each
    dim3 grid(BN / 8);          // 1024 blocks -> 4 blocks/CU, 8 waves/SIMD
    sim_kernel<<<grid, block, 0, stream>>>(points, ctx, dist, imask, gmd,
                                           W1, b1, W2, b2, Wa, ba, out);
}